// Round 1
// baseline (580.177 us; speedup 1.0000x reference)
//
#include <hip/hip_runtime.h>
#include <cmath>

// ---------------- Gaussian windows (host-computed, passed by value) ----------
struct GW7  { float g[7];  };
struct GW11 { float g[11]; };
struct GW29 { float g[29]; };

static void make_gauss(int ws, double sigma, float* out) {
    double t[32]; double s = 0.0;
    int c = ws / 2;
    for (int i = 0; i < ws; ++i) { double d = i - c; t[i] = exp(-(d * d) / (2.0 * sigma * sigma)); s += t[i]; }
    for (int i = 0; i < ws; ++i) out[i] = (float)(t[i] / s);
}

// Accumulator slots (each striped x64 doubles):
// 0-4: ssim[level]  5-9: mcs[level]  10: l1  11: clr  12-27: me1[b]  28-43: me3[b]
#define ACC_SLOTS 44
#define ACC_BYTES (ACC_SLOTS * 64 * sizeof(double))

__device__ __forceinline__ float poly5(float x) {
    float r = fmaf(1.556091f, x, -1.894404f);
    r = fmaf(r, x, 1.435936f);
    r = fmaf(r, x, -0.173433f);
    r = fmaf(r, x, 0.07633f);
    r = fmaf(r, x, -0.000519f);
    return r;
}

// ---------------- L1 loss: conv-free weighted reduction ----------------------
__global__ __launch_bounds__(256) void l1_kernel(
    const float4* __restrict__ a4, const float4* __restrict__ b4,
    int n4, GW7 gw, double* __restrict__ acc)
{
    float s = 0.f;
    const int stride = gridDim.x * blockDim.x;
    for (int i = blockIdx.x * blockDim.x + threadIdx.x; i < n4; i += stride) {
        float4 a = a4[i], b = b4[i];
        int r  = (i << 2) & (512 * 512 - 1);
        int py = r >> 9;
        int px = r & 511;
        float ry;
        if (py >= 3 && py <= 508) ry = 1.f;
        else {
            ry = 0.f;
            #pragma unroll
            for (int k = 0; k < 7; ++k) { int q = py + 3 - k; if (q >= 0 && q < 512) ry += gw.g[k]; }
        }
        float d0 = fabsf(a.x - b.x), d1 = fabsf(a.y - b.y), d2 = fabsf(a.z - b.z), d3 = fabsf(a.w - b.w);
        if (px >= 3 && px <= 505) {
            s += ry * (d0 + d1 + d2 + d3);
        } else {
            float dx[4] = {d0, d1, d2, d3};
            float tacc = 0.f;
            #pragma unroll
            for (int j = 0; j < 4; ++j) {
                float rx = 0.f;
                #pragma unroll
                for (int k = 0; k < 7; ++k) { int q = px + j + 3 - k; if (q >= 0 && q < 512) rx += gw.g[k]; }
                tacc += rx * dx[j];
            }
            s += ry * tacc;
        }
    }
    __shared__ float red[4];
    #pragma unroll
    for (int o = 32; o > 0; o >>= 1) s += __shfl_down(s, o);
    if ((threadIdx.x & 63) == 0) red[threadIdx.x >> 6] = s;
    __syncthreads();
    if (threadIdx.x == 0) {
        float t = red[0] + red[1] + red[2] + red[3];
        atomicAdd(&acc[10 * 64 + (blockIdx.x & 63)], (double)t);
    }
}

// ---------------- SSIM per level: fused tiled separable conv -----------------
__device__ __forceinline__ void colconv11(const float* __restrict__ R, int y0, int x,
                                          const GW11& gw, float* O)
{
    float v[18];
    #pragma unroll
    for (int l = 0; l < 18; ++l) v[l] = R[(y0 + l) * 32 + x];
    #pragma unroll
    for (int j = 0; j < 8; ++j) {
        float a = 0.f;
        #pragma unroll
        for (int k = 0; k < 11; ++k) a += gw.g[k] * v[j + k];
        O[j] = a;
    }
}

__global__ __launch_bounds__(256) void ssim_kernel(
    const float* __restrict__ imgA, const float* __restrict__ imgB,
    int H, int tpp, int tilesX, GW11 gw, double* __restrict__ acc, int level)
{
    constexpr int TILE = 32, IN = 42;
    __shared__ float sA[IN * IN], sB[IN * IN];
    __shared__ float r1[IN * TILE], r2[IN * TILE], r11[IN * TILE], r22[IN * TILE], r12[IN * TILE];
    __shared__ float red[8];

    const int tid = threadIdx.x;
    const int bid = blockIdx.x;
    const int plane = bid / tpp;
    const int t = bid - plane * tpp;
    const int ty = t / tilesX, tx = t - ty * tilesX;
    const size_t base = (size_t)plane * H * H;
    const int oy = ty * TILE - 5, ox = tx * TILE - 5;

    for (int i = tid; i < IN * IN; i += 256) {
        int y = i / IN, x = i - y * IN;
        int gy = oy + y, gx = ox + x;
        bool ok = (gy >= 0) && (gy < H) && (gx >= 0) && (gx < H);
        size_t o = base + (size_t)gy * H + gx;
        sA[i] = ok ? imgA[o] : 0.f;
        sB[i] = ok ? imgB[o] : 0.f;
    }
    __syncthreads();

    // Row conv: 42 rows x 4 groups of 8 outputs = 168 items
    if (tid < IN * 4) {
        int y = tid >> 2, x0 = (tid & 3) * 8;
        float vA[18], vB[18];
        #pragma unroll
        for (int l = 0; l < 18; ++l) { vA[l] = sA[y * IN + x0 + l]; vB[l] = sB[y * IN + x0 + l]; }
        #pragma unroll
        for (int j = 0; j < 8; ++j) {
            float a1 = 0, a2 = 0, a11 = 0, a22 = 0, a12 = 0;
            #pragma unroll
            for (int k = 0; k < 11; ++k) {
                float g = gw.g[k];
                float u1 = vA[j + k], u2 = vB[j + k];
                float t1 = g * u1, t2 = g * u2;
                a1 += t1; a2 += t2; a11 += t1 * u1; a22 += t2 * u2; a12 += t1 * u2;
            }
            int o = y * TILE + x0 + j;
            r1[o] = a1; r2[o] = a2; r11[o] = a11; r22[o] = a22; r12[o] = a12;
        }
    }
    __syncthreads();

    float lss = 0.f, lmc = 0.f;
    // Col conv: 4 groups of 8 rows x 32 cols = 128 items
    if (tid < 128) {
        int y0 = (tid >> 5) * 8, x = tid & 31;
        float muA[8], muB[8], qAA[8], qBB[8], qAB[8];
        colconv11(r1, y0, x, gw, muA);
        colconv11(r2, y0, x, gw, muB);
        colconv11(r11, y0, x, gw, qAA);
        colconv11(r22, y0, x, gw, qBB);
        colconv11(r12, y0, x, gw, qAB);
        #pragma unroll
        for (int j = 0; j < 8; ++j) {
            float m1 = muA[j], m2 = muB[j];
            float s1 = qAA[j] - m1 * m1;
            float s2 = qBB[j] - m2 * m2;
            float s12 = qAB[j] - m1 * m2;
            float V1 = 2.f * s12 + 58.5225f;
            float V2 = s1 + s2 + 58.5225f;
            float num = (2.f * m1 * m2 + 6.5025f) * V1;
            float den = (m1 * m1 + m2 * m2 + 6.5025f) * V2;
            lss += num / den;
            lmc += V1 / V2;
        }
    }
    #pragma unroll
    for (int o = 32; o > 0; o >>= 1) { lss += __shfl_down(lss, o); lmc += __shfl_down(lmc, o); }
    if ((tid & 63) == 0) { red[(tid >> 6) * 2] = lss; red[(tid >> 6) * 2 + 1] = lmc; }
    __syncthreads();
    if (tid == 0) {
        float a = red[0] + red[2] + red[4] + red[6];
        float m = red[1] + red[3] + red[5] + red[7];
        int stripe = bid & 63;
        atomicAdd(&acc[(0 + level) * 64 + stripe], (double)a);
        atomicAdd(&acc[(5 + level) * 64 + stripe], (double)m);
    }
}

// ---------------- 2x2 average pool (both images in one launch) ---------------
__global__ __launch_bounds__(256) void pool_kernel(
    const float* __restrict__ inA, float* __restrict__ outA,
    const float* __restrict__ inB, float* __restrict__ outB,
    int Ho, int n)
{
    const int Wi = Ho * 2;
    const int hw = Ho * Ho;
    const int stride = gridDim.x * blockDim.x;
    for (int idx = blockIdx.x * blockDim.x + threadIdx.x; idx < 2 * n; idx += stride) {
        int k = idx;
        const float2* in2; float* o;
        if (k < n) { in2 = (const float2*)inA; o = outA; }
        else       { k -= n; in2 = (const float2*)inB; o = outB; }
        int p = k / hw; int r = k - p * hw;
        int y = r / Ho; int x = r - y * Ho;
        size_t b2 = (size_t)p * (size_t)(Wi * (Wi / 2)) + (size_t)y * Wi + x;
        float2 u = in2[b2];
        float2 v = in2[b2 + (Wi >> 1)];
        o[k] = 0.25f * ((u.x + u.y) + (v.x + v.y));
    }
}

// ---------------- CLR loss: 29-tap fused tiled conv, two stages --------------
template<int STAGE>
__global__ __launch_bounds__(256) void clr_kernel(
    const float* __restrict__ img1, const float* __restrict__ img3,
    GW29 gw, double* __restrict__ acc)
{
    constexpr int TILE = 32, IN = 60, H = 512;
    __shared__ float s1[IN * IN], s3[IN * IN];
    __shared__ float r1[IN * TILE], r3[IN * TILE];
    __shared__ float red[8];
    __shared__ float sc_sh;

    const int tid = threadIdx.x;
    const int bid = blockIdx.x;
    const int plane = bid >> 8;           // 256 tiles per 512x512 plane
    const int t = bid & 255;
    const int ty = t >> 4, tx = t & 15;
    const int b = plane / 3, c = plane - b * 3;
    const float wg = (c == 0) ? 0.299f : (c == 1 ? 0.587f : 0.144f);
    const size_t base = (size_t)plane * (H * H);
    const int oy = ty * TILE - 14, ox = tx * TILE - 14;

    if (STAGE == 1 && tid < 64) {
        double m1 = acc[(12 + b) * 64 + tid];
        double m3 = acc[(28 + b) * 64 + tid];
        #pragma unroll
        for (int o = 32; o > 0; o >>= 1) { m1 += __shfl_down(m1, o); m3 += __shfl_down(m3, o); }
        if (tid == 0) sc_sh = (float)(m1 / m3);
    }

    for (int i = tid; i < IN * IN; i += 256) {
        int y = i / IN, x = i - y * IN;
        int gy = oy + y, gx = ox + x;
        bool ok = (gy >= 0) && (gy < H) && (gx >= 0) && (gx < H);
        size_t o = base + (size_t)gy * H + gx;
        s1[i] = ok ? img1[o] : 0.f;
        s3[i] = ok ? img3[o] : 0.f;
    }
    __syncthreads();

    // Row conv: 60 rows x 4 groups of 8 = 240 items
    if (tid < 240) {
        int y = tid >> 2, x0 = (tid & 3) * 8;
        float v[36];
        #pragma unroll
        for (int l = 0; l < 36; ++l) v[l] = s1[y * IN + x0 + l];
        #pragma unroll
        for (int j = 0; j < 8; ++j) {
            float a = 0.f;
            #pragma unroll
            for (int k = 0; k < 29; ++k) a += gw.g[k] * v[j + k];
            r1[y * TILE + x0 + j] = a;
        }
        #pragma unroll
        for (int l = 0; l < 36; ++l) v[l] = s3[y * IN + x0 + l];
        #pragma unroll
        for (int j = 0; j < 8; ++j) {
            float a = 0.f;
            #pragma unroll
            for (int k = 0; k < 29; ++k) a += gw.g[k] * v[j + k];
            r3[y * TILE + x0 + j] = a;
        }
    }
    __syncthreads();

    float p1 = 0.f, p3 = 0.f;
    if (tid < 128) {
        int y0 = (tid >> 5) * 8, x = tid & 31;
        float mu1o[8], mu3o[8];
        {
            float v[36];
            #pragma unroll
            for (int l = 0; l < 36; ++l) v[l] = r1[(y0 + l) * TILE + x];
            #pragma unroll
            for (int j = 0; j < 8; ++j) {
                float a = 0.f;
                #pragma unroll
                for (int k = 0; k < 29; ++k) a += gw.g[k] * v[j + k];
                mu1o[j] = a;
            }
        }
        {
            float v[36];
            #pragma unroll
            for (int l = 0; l < 36; ++l) v[l] = r3[(y0 + l) * TILE + x];
            #pragma unroll
            for (int j = 0; j < 8; ++j) {
                float a = 0.f;
                #pragma unroll
                for (int k = 0; k < 29; ++k) a += gw.g[k] * v[j + k];
                mu3o[j] = a;
            }
        }
        float sc = (STAGE == 1) ? sc_sh : 0.f;
        #pragma unroll
        for (int j = 0; j < 8; ++j) {
            float p = poly5(mu1o[j]);
            if (STAGE == 0) { p1 += wg * p; p3 += wg * mu3o[j]; }
            else            { p1 += fabsf(p - mu3o[j] * sc); }
        }
    }
    #pragma unroll
    for (int o = 32; o > 0; o >>= 1) { p1 += __shfl_down(p1, o); p3 += __shfl_down(p3, o); }
    if ((tid & 63) == 0) { red[(tid >> 6) * 2] = p1; red[(tid >> 6) * 2 + 1] = p3; }
    __syncthreads();
    if (tid == 0) {
        float a1 = red[0] + red[2] + red[4] + red[6];
        int stripe = bid & 63;
        if (STAGE == 0) {
            float a3 = red[1] + red[3] + red[5] + red[7];
            atomicAdd(&acc[(12 + b) * 64 + stripe], (double)a1);
            atomicAdd(&acc[(28 + b) * 64 + stripe], (double)a3);
        } else {
            atomicAdd(&acc[11 * 64 + stripe], (double)a1);
        }
    }
}

// ---------------- Finalize: combine everything into the scalar ---------------
__global__ void finalize_kernel(const double* __restrict__ acc, float* __restrict__ out)
{
    __shared__ double sums[ACC_SLOTS];
    int t = threadIdx.x;
    if (t < ACC_SLOTS) {
        double s = 0.0;
        for (int i = 0; i < 64; ++i) s += acc[t * 64 + i];
        sums[t] = s;
    }
    __syncthreads();
    if (t == 0) {
        const double w[5] = {0.0448, 0.2856, 0.3001, 0.2363, 0.1333};
        double value = 1.0;
        for (int l = 0; l < 5; ++l) {
            double dim = (double)(512 >> l);
            double cnt = 48.0 * dim * dim;
            double mval = (l < 4) ? (sums[5 + l] / cnt) : (sums[l] / cnt);
            value *= pow(mval, w[l]);
        }
        double n0 = 48.0 * 512.0 * 512.0;
        double l1v = sums[10] / n0;
        double clrv = sums[11] / n0;
        out[0] = (float)(0.4 * (1.0 - value) + 0.4 * l1v + 0.2 * clrv);
    }
}

// ---------------- Launch ------------------------------------------------------
extern "C" void kernel_launch(void* const* d_in, const int* in_sizes, int n_in,
                              void* d_out, int out_size, void* d_ws, size_t ws_size,
                              hipStream_t stream)
{
    (void)in_sizes; (void)n_in; (void)out_size; (void)ws_size;
    const float* img1 = (const float*)d_in[0];
    const float* img2 = (const float*)d_in[1];
    const float* img3 = (const float*)d_in[2];
    float* out = (float*)d_out;
    double* acc = (double*)d_ws;

    GW11 g11; make_gauss(11, 1.5, g11.g);
    GW7  g7;  make_gauss(7, 1.1, g7.g);
    GW29 g29; make_gauss(29, 29.0 / 6.0, g29.g);

    hipMemsetAsync(d_ws, 0, ACC_BYTES, stream);

    // L1 term (pure reduction)
    l1_kernel<<<2048, 256, 0, stream>>>((const float4*)img1, (const float4*)img2,
                                        (16 * 3 * 512 * 512) / 4, g7, acc);

    // MS-SSIM: 5 levels with interleaved 2x2 pooling into workspace pyramid
    float* pyr = (float*)((char*)d_ws + 32768);
    const size_t PYR1 = (size_t)16 * 3 * (256 * 256 + 128 * 128 + 64 * 64 + 32 * 32);
    float* pyrA = pyr;
    float* pyrB = pyr + PYR1;

    const float* curA = img1; const float* curB = img2;
    int H = 512; size_t off = 0;
    for (int l = 0; l < 5; ++l) {
        int tilesX = H / 32; int tpp = tilesX * tilesX;
        ssim_kernel<<<48 * tpp, 256, 0, stream>>>(curA, curB, H, tpp, tilesX, g11, acc, l);
        if (l < 4) {
            int Ho = H / 2; int n = 48 * Ho * Ho;
            float* dA = pyrA + off; float* dB = pyrB + off;
            int blocks = (2 * n + 255) / 256; if (blocks > 4096) blocks = 4096;
            pool_kernel<<<blocks, 256, 0, stream>>>(curA, dA, curB, dB, Ho, n);
            curA = dA; curB = dB; off += (size_t)n; H = Ho;
        }
    }

    // CLR: stage 0 accumulates per-batch gray means, stage 1 the final |.| mean
    clr_kernel<0><<<12288, 256, 0, stream>>>(img1, img3, g29, acc);
    clr_kernel<1><<<12288, 256, 0, stream>>>(img1, img3, g29, acc);

    finalize_kernel<<<1, 64, 0, stream>>>(acc, out);
}

// Round 2
// 417.632 us; speedup vs baseline: 1.3892x; 1.3892x over previous
//
#include <hip/hip_runtime.h>
#include <hip/hip_fp16.h>
#include <cmath>

// ---------------- Gaussian windows (host-computed, passed by value) ----------
struct GW7  { float g[7];  };
struct GW11 { float g[11]; };
struct GW29 { float g[29]; };

static void make_gauss(int ws, double sigma, float* out) {
    double t[32]; double s = 0.0;
    int c = ws / 2;
    for (int i = 0; i < ws; ++i) { double d = i - c; t[i] = exp(-(d * d) / (2.0 * sigma * sigma)); s += t[i]; }
    for (int i = 0; i < ws; ++i) out[i] = (float)(t[i] / s);
}

// Accumulator slots (each striped x64 doubles):
// 0-4: ssim[level]  5-9: mcs[level]  10: l1  11: clr  12-27: me1[b]  28-43: me3[b]
#define ACC_SLOTS 44
#define ACC_BYTES (ACC_SLOTS * 64 * sizeof(double))

__device__ __forceinline__ float poly5(float x) {
    float r = fmaf(1.556091f, x, -1.894404f);
    r = fmaf(r, x, 1.435936f);
    r = fmaf(r, x, -0.173433f);
    r = fmaf(r, x, 0.07633f);
    r = fmaf(r, x, -0.000519f);
    return r;
}

// ---------------- L1 loss: conv-free weighted reduction ----------------------
__global__ __launch_bounds__(256) void l1_kernel(
    const float4* __restrict__ a4, const float4* __restrict__ b4,
    int n4, GW7 gw, double* __restrict__ acc)
{
    float s = 0.f;
    const int stride = gridDim.x * blockDim.x;
    for (int i = blockIdx.x * blockDim.x + threadIdx.x; i < n4; i += stride) {
        float4 a = a4[i], b = b4[i];
        int r  = (i << 2) & (512 * 512 - 1);
        int py = r >> 9;
        int px = r & 511;
        float ry;
        if (py >= 3 && py <= 508) ry = 1.f;
        else {
            ry = 0.f;
            #pragma unroll
            for (int k = 0; k < 7; ++k) { int q = py + 3 - k; if (q >= 0 && q < 512) ry += gw.g[k]; }
        }
        float d0 = fabsf(a.x - b.x), d1 = fabsf(a.y - b.y), d2 = fabsf(a.z - b.z), d3 = fabsf(a.w - b.w);
        if (px >= 3 && px <= 505) {
            s += ry * (d0 + d1 + d2 + d3);
        } else {
            float dx[4] = {d0, d1, d2, d3};
            float tacc = 0.f;
            #pragma unroll
            for (int j = 0; j < 4; ++j) {
                float rx = 0.f;
                #pragma unroll
                for (int k = 0; k < 7; ++k) { int q = px + j + 3 - k; if (q >= 0 && q < 512) rx += gw.g[k]; }
                tacc += rx * dx[j];
            }
            s += ry * tacc;
        }
    }
    __shared__ float red[4];
    #pragma unroll
    for (int o = 32; o > 0; o >>= 1) s += __shfl_down(s, o);
    if ((threadIdx.x & 63) == 0) red[threadIdx.x >> 6] = s;
    __syncthreads();
    if (threadIdx.x == 0) {
        float t = red[0] + red[1] + red[2] + red[3];
        atomicAdd(&acc[10 * 64 + (blockIdx.x & 63)], (double)t);
    }
}

// ---------------- me3: conv-free weighted mean of img3 (29-tap borders) ------
__global__ __launch_bounds__(256) void me3_kernel(
    const float4* __restrict__ img3_4, GW29 gw, double* __restrict__ acc)
{
    __shared__ float red[4];
    const int tid = threadIdx.x, bid = blockIdx.x;
    const int plane = bid >> 5, sub = bid & 31;
    const int b = plane / 3, c = plane - b * 3;
    const float wg = (c == 0) ? 0.299f : (c == 1 ? 0.587f : 0.144f);
    const size_t pbase = (size_t)plane * 65536;
    float s = 0.f;
    #pragma unroll
    for (int it = 0; it < 8; ++it) {
        int i = sub * 2048 + it * 256 + tid;
        float4 a = img3_4[pbase + i];
        int r = i << 2;
        int py = r >> 9, px = r & 511;
        float ry;
        if (py >= 14 && py <= 497) ry = 1.f;
        else {
            ry = 0.f;
            #pragma unroll
            for (int k = 0; k < 29; ++k) { int q = py + 14 - k; if (q >= 0 && q < 512) ry += gw.g[k]; }
        }
        if (px >= 14 && px <= 494) {
            s += ry * ((a.x + a.y) + (a.z + a.w));
        } else {
            float av[4] = {a.x, a.y, a.z, a.w};
            float t = 0.f;
            #pragma unroll
            for (int j = 0; j < 4; ++j) {
                float rx = 0.f;
                #pragma unroll
                for (int k = 0; k < 29; ++k) { int q = px + j + 14 - k; if (q >= 0 && q < 512) rx += gw.g[k]; }
                t += rx * av[j];
            }
            s += ry * t;
        }
    }
    s *= wg;
    #pragma unroll
    for (int o = 32; o > 0; o >>= 1) s += __shfl_down(s, o);
    if ((tid & 63) == 0) red[tid >> 6] = s;
    __syncthreads();
    if (tid == 0)
        atomicAdd(&acc[(28 + b) * 64 + (bid & 63)], (double)(red[0] + red[1] + red[2] + red[3]));
}

// ---------------- SSIM per level: fused tiled separable conv -----------------
__global__ __launch_bounds__(256) void ssim_kernel(
    const float* __restrict__ imgA, const float* __restrict__ imgB,
    int H, int tpp, int tilesX, GW11 gw, double* __restrict__ acc, int level)
{
    constexpr int TILE = 32, IN = 42, SP = 43, RP = 33;
    __shared__ float sA[IN * SP], sB[IN * SP];
    __shared__ float r1[IN * RP], r2[IN * RP], r11[IN * RP], r22[IN * RP], r12[IN * RP];
    __shared__ float red[8];

    const int tid = threadIdx.x;
    const int bid = blockIdx.x;
    const int plane = bid / tpp;
    const int t = bid - plane * tpp;
    const int ty = t / tilesX, tx = t - ty * tilesX;
    const size_t base = (size_t)plane * H * H;
    const int oy = ty * TILE - 5, ox = tx * TILE - 5;

    for (int i = tid; i < IN * IN; i += 256) {
        int y = i / IN, x = i - y * IN;
        int gy = oy + y, gx = ox + x;
        bool ok = (gy >= 0) && (gy < H) && (gx >= 0) && (gx < H);
        size_t o = base + (size_t)gy * H + gx;
        sA[y * SP + x] = ok ? imgA[o] : 0.f;
        sB[y * SP + x] = ok ? imgB[o] : 0.f;
    }
    __syncthreads();

    // Row conv: 42 rows x 4 groups of 8 outputs = 168 items
    if (tid < IN * 4) {
        int y = tid >> 2, x0 = (tid & 3) * 8;
        float vA[18], vB[18];
        #pragma unroll
        for (int l = 0; l < 18; ++l) { vA[l] = sA[y * SP + x0 + l]; vB[l] = sB[y * SP + x0 + l]; }
        #pragma unroll
        for (int j = 0; j < 8; ++j) {
            float a1 = 0, a2 = 0, a11 = 0, a22 = 0, a12 = 0;
            #pragma unroll
            for (int k = 0; k < 11; ++k) {
                float g = gw.g[k];
                float u1 = vA[j + k], u2 = vB[j + k];
                float t1 = g * u1, t2 = g * u2;
                a1 += t1; a2 += t2; a11 += t1 * u1; a22 += t2 * u2; a12 += t1 * u2;
            }
            int o = y * RP + x0 + j;
            r1[o] = a1; r2[o] = a2; r11[o] = a11; r22[o] = a22; r12[o] = a12;
        }
    }
    __syncthreads();

    // Col conv: all 256 threads, 4 outputs each
    const int y0 = (tid >> 5) * 4, x = tid & 31;
    float lss = 0.f, lmc = 0.f;
    {
        auto cconv = [&](const float* R, float* O) {
            float v[14];
            #pragma unroll
            for (int l = 0; l < 14; ++l) v[l] = R[(y0 + l) * RP + x];
            #pragma unroll
            for (int j = 0; j < 4; ++j) {
                float a = 0.f;
                #pragma unroll
                for (int k = 0; k < 11; ++k) a = fmaf(gw.g[k], v[j + k], a);
                O[j] = a;
            }
        };
        float muA[4], muB[4], qAA[4], qBB[4], qAB[4];
        cconv(r1, muA); cconv(r2, muB); cconv(r11, qAA); cconv(r22, qBB); cconv(r12, qAB);
        #pragma unroll
        for (int j = 0; j < 4; ++j) {
            float m1 = muA[j], m2 = muB[j];
            float s1 = qAA[j] - m1 * m1;
            float s2 = qBB[j] - m2 * m2;
            float s12 = qAB[j] - m1 * m2;
            float V1 = 2.f * s12 + 58.5225f;
            float V2 = s1 + s2 + 58.5225f;
            float num = (2.f * m1 * m2 + 6.5025f) * V1;
            float den = (m1 * m1 + m2 * m2 + 6.5025f) * V2;
            lss += num / den;
            lmc += V1 / V2;
        }
    }
    #pragma unroll
    for (int o = 32; o > 0; o >>= 1) { lss += __shfl_down(lss, o); lmc += __shfl_down(lmc, o); }
    if ((tid & 63) == 0) { red[(tid >> 6) * 2] = lss; red[(tid >> 6) * 2 + 1] = lmc; }
    __syncthreads();
    if (tid == 0) {
        float a = red[0] + red[2] + red[4] + red[6];
        float m = red[1] + red[3] + red[5] + red[7];
        int stripe = bid & 63;
        atomicAdd(&acc[(0 + level) * 64 + stripe], (double)a);
        atomicAdd(&acc[(5 + level) * 64 + stripe], (double)m);
    }
}

// ---------------- 2x2 average pool (both images in one launch) ---------------
__global__ __launch_bounds__(256) void pool_kernel(
    const float* __restrict__ inA, float* __restrict__ outA,
    const float* __restrict__ inB, float* __restrict__ outB,
    int Ho, int n)
{
    const int Wi = Ho * 2;
    const int hw = Ho * Ho;
    const int stride = gridDim.x * blockDim.x;
    for (int idx = blockIdx.x * blockDim.x + threadIdx.x; idx < 2 * n; idx += stride) {
        int k = idx;
        const float2* in2; float* o;
        if (k < n) { in2 = (const float2*)inA; o = outA; }
        else       { k -= n; in2 = (const float2*)inB; o = outB; }
        int p = k / hw; int r = k - p * hw;
        int y = r / Ho; int x = r - y * Ho;
        size_t b2 = (size_t)p * (size_t)(Wi * (Wi / 2)) + (size_t)y * Wi + x;
        float2 u = in2[b2];
        float2 v = in2[b2 + (Wi >> 1)];
        o[k] = 0.25f * ((u.x + u.y) + (v.x + v.y));
    }
}

// ---------------- CLR loss: 29-tap fused tiled separable conv ----------------
#define CLR_IN 60
#define CLR_SP 61
#define CLR_RP 33

__device__ __forceinline__ void clr_load_tile(const float* __restrict__ img, float* s,
                                              int tid, int oy, int ox, size_t base)
{
    for (int i = tid; i < CLR_IN * CLR_IN; i += 256) {
        int y = i / CLR_IN, x = i - y * CLR_IN;
        int gy = oy + y, gx = ox + x;
        bool ok = (gy >= 0) && (gy < 512) && (gx >= 0) && (gx < 512);
        s[y * CLR_SP + x] = ok ? img[base + (size_t)gy * 512 + gx] : 0.f;
    }
}

__device__ __forceinline__ void clr_rowconv(const float* s, float* rbuf, const GW29& gw, int tid)
{
    if (tid < 240) {
        int y = tid >> 2, x0 = (tid & 3) * 8;
        float v[36];
        #pragma unroll
        for (int l = 0; l < 36; ++l) v[l] = s[y * CLR_SP + x0 + l];
        #pragma unroll
        for (int j = 0; j < 8; ++j) {
            float a = 0.f;
            #pragma unroll
            for (int k = 0; k < 29; ++k) a = fmaf(gw.g[k], v[j + k], a);
            rbuf[y * CLR_RP + x0 + j] = a;
        }
    }
}

__device__ __forceinline__ void clr_colconv(const float* rbuf, const GW29& gw, int y0, int x, float mu[4])
{
    float v[32];
    #pragma unroll
    for (int l = 0; l < 32; ++l) v[l] = rbuf[(y0 + l) * CLR_RP + x];
    #pragma unroll
    for (int j = 0; j < 4; ++j) {
        float a = 0.f;
        #pragma unroll
        for (int k = 0; k < 29; ++k) a = fmaf(gw.g[k], v[j + k], a);
        mu[j] = a;
    }
}

template<bool STOREP>
__global__ __launch_bounds__(256) void clr_stage0(
    const float* __restrict__ img1, __half* __restrict__ pbuf,
    GW29 gw, double* __restrict__ acc)
{
    __shared__ float s[CLR_IN * CLR_SP];
    __shared__ float rbuf[CLR_IN * CLR_RP];
    __shared__ float red[4];
    const int tid = threadIdx.x, bid = blockIdx.x;
    const int plane = bid >> 8, t = bid & 255;
    const int ty = t >> 4, tx = t & 15;
    const int b = plane / 3, c = plane - b * 3;
    const float wg = (c == 0) ? 0.299f : (c == 1 ? 0.587f : 0.144f);
    const size_t base = (size_t)plane * (512 * 512);

    clr_load_tile(img1, s, tid, ty * 32 - 14, tx * 32 - 14, base);
    __syncthreads();
    clr_rowconv(s, rbuf, gw, tid);
    __syncthreads();
    const int y0 = (tid >> 5) * 4, x = tid & 31;
    float mu[4];
    clr_colconv(rbuf, gw, y0, x, mu);
    float part = 0.f;
    #pragma unroll
    for (int j = 0; j < 4; ++j) {
        float p = poly5(mu[j]);
        part += p;
        if (STOREP)
            pbuf[base + (size_t)(ty * 32 + y0 + j) * 512 + (tx * 32 + x)] = __float2half(p);
    }
    part *= wg;
    #pragma unroll
    for (int o = 32; o > 0; o >>= 1) part += __shfl_down(part, o);
    if ((tid & 63) == 0) red[tid >> 6] = part;
    __syncthreads();
    if (tid == 0)
        atomicAdd(&acc[(12 + b) * 64 + (bid & 63)], (double)(red[0] + red[1] + red[2] + red[3]));
}

template<bool LOADP>
__global__ __launch_bounds__(256) void clr_stage1(
    const float* __restrict__ img1, const float* __restrict__ img3,
    const __half* __restrict__ pbuf, GW29 gw, double* __restrict__ acc)
{
    __shared__ float s[CLR_IN * CLR_SP];
    __shared__ float rbuf[CLR_IN * CLR_RP];
    __shared__ float red[4];
    __shared__ float sc_sh;
    const int tid = threadIdx.x, bid = blockIdx.x;
    const int plane = bid >> 8, t = bid & 255;
    const int ty = t >> 4, tx = t & 15;
    const int b = plane / 3;
    const size_t base = (size_t)plane * (512 * 512);

    if (tid < 64) {
        double m1 = acc[(12 + b) * 64 + tid];
        double m3 = acc[(28 + b) * 64 + tid];
        #pragma unroll
        for (int o = 32; o > 0; o >>= 1) { m1 += __shfl_down(m1, o); m3 += __shfl_down(m3, o); }
        if (tid == 0) sc_sh = (float)(m1 / m3);
    }

    const int y0 = (tid >> 5) * 4, x = tid & 31;
    float pre[4];
    if (!LOADP) {
        clr_load_tile(img1, s, tid, ty * 32 - 14, tx * 32 - 14, base);
        __syncthreads();
        clr_rowconv(s, rbuf, gw, tid);
        __syncthreads();
        float mu1[4];
        clr_colconv(rbuf, gw, y0, x, mu1);
        #pragma unroll
        for (int j = 0; j < 4; ++j) pre[j] = poly5(mu1[j]);
        __syncthreads();
    }
    clr_load_tile(img3, s, tid, ty * 32 - 14, tx * 32 - 14, base);
    __syncthreads();
    clr_rowconv(s, rbuf, gw, tid);
    __syncthreads();
    float mu3[4];
    clr_colconv(rbuf, gw, y0, x, mu3);
    if (LOADP) {
        #pragma unroll
        for (int j = 0; j < 4; ++j)
            pre[j] = __half2float(pbuf[base + (size_t)(ty * 32 + y0 + j) * 512 + (tx * 32 + x)]);
    }
    const float sc = sc_sh;
    float t1 = 0.f;
    #pragma unroll
    for (int j = 0; j < 4; ++j) t1 += fabsf(pre[j] - mu3[j] * sc);
    #pragma unroll
    for (int o = 32; o > 0; o >>= 1) t1 += __shfl_down(t1, o);
    if ((tid & 63) == 0) red[tid >> 6] = t1;
    __syncthreads();
    if (tid == 0)
        atomicAdd(&acc[11 * 64 + (bid & 63)], (double)(red[0] + red[1] + red[2] + red[3]));
}

// ---------------- Finalize: combine everything into the scalar ---------------
__global__ void finalize_kernel(const double* __restrict__ acc, float* __restrict__ out)
{
    __shared__ double sums[ACC_SLOTS];
    int t = threadIdx.x;
    if (t < ACC_SLOTS) {
        double s = 0.0;
        for (int i = 0; i < 64; ++i) s += acc[t * 64 + i];
        sums[t] = s;
    }
    __syncthreads();
    if (t == 0) {
        const double w[5] = {0.0448, 0.2856, 0.3001, 0.2363, 0.1333};
        double value = 1.0;
        for (int l = 0; l < 5; ++l) {
            double dim = (double)(512 >> l);
            double cnt = 48.0 * dim * dim;
            double mval = (l < 4) ? (sums[5 + l] / cnt) : (sums[l] / cnt);
            value *= pow(mval, w[l]);
        }
        double n0 = 48.0 * 512.0 * 512.0;
        double l1v = sums[10] / n0;
        double clrv = sums[11] / n0;
        out[0] = (float)(0.4 * (1.0 - value) + 0.4 * l1v + 0.2 * clrv);
    }
}

// ---------------- Launch ------------------------------------------------------
extern "C" void kernel_launch(void* const* d_in, const int* in_sizes, int n_in,
                              void* d_out, int out_size, void* d_ws, size_t ws_size,
                              hipStream_t stream)
{
    (void)in_sizes; (void)n_in; (void)out_size;
    const float* img1 = (const float*)d_in[0];
    const float* img2 = (const float*)d_in[1];
    const float* img3 = (const float*)d_in[2];
    float* out = (float*)d_out;
    double* acc = (double*)d_ws;

    GW11 g11; make_gauss(11, 1.5, g11.g);
    GW7  g7;  make_gauss(7, 1.1, g7.g);
    GW29 g29; make_gauss(29, 29.0 / 6.0, g29.g);

    hipMemsetAsync(d_ws, 0, ACC_BYTES, stream);

    // L1 term + me3 (both conv-free reductions)
    l1_kernel<<<2048, 256, 0, stream>>>((const float4*)img1, (const float4*)img2,
                                        (16 * 3 * 512 * 512) / 4, g7, acc);
    me3_kernel<<<1536, 256, 0, stream>>>((const float4*)img3, g29, acc);

    // MS-SSIM: 5 levels with interleaved 2x2 pooling into workspace pyramid
    float* pyr = (float*)((char*)d_ws + 32768);
    const size_t PYR1 = (size_t)16 * 3 * (256 * 256 + 128 * 128 + 64 * 64 + 32 * 32);
    float* pyrA = pyr;
    float* pyrB = pyr + PYR1;

    const float* curA = img1; const float* curB = img2;
    int H = 512; size_t off = 0;
    for (int l = 0; l < 5; ++l) {
        int tilesX = H / 32; int tpp = tilesX * tilesX;
        ssim_kernel<<<48 * tpp, 256, 0, stream>>>(curA, curB, H, tpp, tilesX, g11, acc, l);
        if (l < 4) {
            int Ho = H / 2; int n = 48 * Ho * Ho;
            float* dA = pyrA + off; float* dB = pyrB + off;
            int blocks = (2 * n + 255) / 256; if (blocks > 4096) blocks = 4096;
            pool_kernel<<<blocks, 256, 0, stream>>>(curA, dA, curB, dB, Ho, n);
            curA = dA; curB = dB; off += (size_t)n; H = Ho;
        }
    }

    // CLR: stage0 conv(img1)->p (+me1); stage1 conv(img3)+|p - mu3*sc|
    const size_t poff = 32768 + PYR1 * 2 * sizeof(float);
    const size_t PBYTES = (size_t)48 * 512 * 512 * sizeof(__half);
    __half* pbuf = (__half*)((char*)d_ws + poff);
    if (ws_size >= poff + PBYTES) {
        clr_stage0<true><<<12288, 256, 0, stream>>>(img1, pbuf, g29, acc);
        clr_stage1<true><<<12288, 256, 0, stream>>>(img1, img3, pbuf, g29, acc);
    } else {
        clr_stage0<false><<<12288, 256, 0, stream>>>(img1, pbuf, g29, acc);
        clr_stage1<false><<<12288, 256, 0, stream>>>(img1, img3, pbuf, g29, acc);
    }

    finalize_kernel<<<1, 64, 0, stream>>>(acc, out);
}

// Round 3
// 362.648 us; speedup vs baseline: 1.5998x; 1.1516x over previous
//
#include <hip/hip_runtime.h>
#include <hip/hip_fp16.h>
#include <cmath>

// ---------------- Gaussian windows (host-computed, passed by value) ----------
struct GW7  { float g[7];  };
struct GW11 { float g[11]; };
struct GW29 { float g[29]; };

static void make_gauss(int ws, double sigma, float* out) {
    double t[32]; double s = 0.0;
    int c = ws / 2;
    for (int i = 0; i < ws; ++i) { double d = i - c; t[i] = exp(-(d * d) / (2.0 * sigma * sigma)); s += t[i]; }
    for (int i = 0; i < ws; ++i) out[i] = (float)(t[i] / s);
}

// Accumulator slots (each striped x64 doubles):
// 0-4: ssim[level]  5-9: mcs[level]  10: l1  11: clr  12-27: me1[b]  28-43: me3[b]
#define ACC_SLOTS 44
#define ACC_BYTES (ACC_SLOTS * 64 * sizeof(double))

__device__ __forceinline__ float poly5(float x) {
    float r = fmaf(1.556091f, x, -1.894404f);
    r = fmaf(r, x, 1.435936f);
    r = fmaf(r, x, -0.173433f);
    r = fmaf(r, x, 0.07633f);
    r = fmaf(r, x, -0.000519f);
    return r;
}

// ---------------- L1 loss: conv-free weighted reduction ----------------------
__global__ __launch_bounds__(256) void l1_kernel(
    const float4* __restrict__ a4, const float4* __restrict__ b4,
    int n4, GW7 gw, double* __restrict__ acc)
{
    float s = 0.f;
    const int stride = gridDim.x * blockDim.x;
    for (int i = blockIdx.x * blockDim.x + threadIdx.x; i < n4; i += stride) {
        float4 a = a4[i], b = b4[i];
        int r  = (i << 2) & (512 * 512 - 1);
        int py = r >> 9;
        int px = r & 511;
        float ry;
        if (py >= 3 && py <= 508) ry = 1.f;
        else {
            ry = 0.f;
            #pragma unroll
            for (int k = 0; k < 7; ++k) { int q = py + 3 - k; if (q >= 0 && q < 512) ry += gw.g[k]; }
        }
        float d0 = fabsf(a.x - b.x), d1 = fabsf(a.y - b.y), d2 = fabsf(a.z - b.z), d3 = fabsf(a.w - b.w);
        if (px >= 3 && px <= 505) {
            s += ry * (d0 + d1 + d2 + d3);
        } else {
            float dx[4] = {d0, d1, d2, d3};
            float tacc = 0.f;
            #pragma unroll
            for (int j = 0; j < 4; ++j) {
                float rx = 0.f;
                #pragma unroll
                for (int k = 0; k < 7; ++k) { int q = px + j + 3 - k; if (q >= 0 && q < 512) rx += gw.g[k]; }
                tacc += rx * dx[j];
            }
            s += ry * tacc;
        }
    }
    __shared__ float red[4];
    #pragma unroll
    for (int o = 32; o > 0; o >>= 1) s += __shfl_down(s, o);
    if ((threadIdx.x & 63) == 0) red[threadIdx.x >> 6] = s;
    __syncthreads();
    if (threadIdx.x == 0) {
        float t = red[0] + red[1] + red[2] + red[3];
        atomicAdd(&acc[10 * 64 + (blockIdx.x & 63)], (double)t);
    }
}

// ---------------- me3: conv-free weighted mean of img3 (29-tap borders) ------
__global__ __launch_bounds__(256) void me3_kernel(
    const float4* __restrict__ img3_4, GW29 gw, double* __restrict__ acc)
{
    __shared__ float red[4];
    const int tid = threadIdx.x, bid = blockIdx.x;
    const int plane = bid >> 5, sub = bid & 31;
    const int b = plane / 3, c = plane - b * 3;
    const float wg = (c == 0) ? 0.299f : (c == 1 ? 0.587f : 0.144f);
    const size_t pbase = (size_t)plane * 65536;
    float s = 0.f;
    #pragma unroll
    for (int it = 0; it < 8; ++it) {
        int i = sub * 2048 + it * 256 + tid;
        float4 a = img3_4[pbase + i];
        int r = i << 2;
        int py = r >> 9, px = r & 511;
        float ry;
        if (py >= 14 && py <= 497) ry = 1.f;
        else {
            ry = 0.f;
            #pragma unroll
            for (int k = 0; k < 29; ++k) { int q = py + 14 - k; if (q >= 0 && q < 512) ry += gw.g[k]; }
        }
        if (px >= 14 && px <= 494) {
            s += ry * ((a.x + a.y) + (a.z + a.w));
        } else {
            float av[4] = {a.x, a.y, a.z, a.w};
            float t = 0.f;
            #pragma unroll
            for (int j = 0; j < 4; ++j) {
                float rx = 0.f;
                #pragma unroll
                for (int k = 0; k < 29; ++k) { int q = px + j + 14 - k; if (q >= 0 && q < 512) rx += gw.g[k]; }
                t += rx * av[j];
            }
            s += ry * t;
        }
    }
    s *= wg;
    #pragma unroll
    for (int o = 32; o > 0; o >>= 1) s += __shfl_down(s, o);
    if ((tid & 63) == 0) red[tid >> 6] = s;
    __syncthreads();
    if (tid == 0)
        atomicAdd(&acc[(28 + b) * 64 + (bid & 63)], (double)(red[0] + red[1] + red[2] + red[3]));
}

// ---------------- SSIM per level: fused tiled separable conv -----------------
// 4 quantities (A, B, A^2+B^2, A*B); LDS union: row buffers overwrite input
// tiles (the 168 row-conv threads hold the whole input in registers).
__global__ __launch_bounds__(256) void ssim_kernel(
    const float* __restrict__ imgA, const float* __restrict__ imgB,
    int H, int tpp, int tilesX, GW11 gw, double* __restrict__ acc, int level)
{
    constexpr int TILE = 32, IN = 42, SP = 43, RP = 33;
    __shared__ float lds[4 * IN * RP];           // 5544 floats = 22.2 KB
    __shared__ float red[8];
    float* sA  = lds;                            // load phase: 42x43
    float* sB  = lds + IN * SP;                  // load phase: 42x43
    float* r1  = lds;                            // conv phase: 42x33 each
    float* r2  = lds + 1 * IN * RP;
    float* rSS = lds + 2 * IN * RP;
    float* r12 = lds + 3 * IN * RP;

    const int tid = threadIdx.x;
    const int bid = blockIdx.x;
    const int plane = bid / tpp;
    const int t = bid - plane * tpp;
    const int ty = t / tilesX, tx = t - ty * tilesX;
    const size_t base = (size_t)plane * H * H;
    const int oy = ty * TILE - 5, ox = tx * TILE - 5;

    for (int i = tid; i < IN * IN; i += 256) {
        int y = i / IN, x = i - y * IN;
        int gy = oy + y, gx = ox + x;
        bool ok = (gy >= 0) && (gy < H) && (gx >= 0) && (gx < H);
        size_t o = base + (size_t)gy * H + gx;
        sA[y * SP + x] = ok ? imgA[o] : 0.f;
        sB[y * SP + x] = ok ? imgB[o] : 0.f;
    }
    __syncthreads();

    // Row conv: 42 rows x 4 groups of 8 outputs = 168 items
    float vA[18], vB[18];
    const int ry = tid >> 2, rx0 = (tid & 3) * 8;
    if (tid < IN * 4) {
        #pragma unroll
        for (int l = 0; l < 18; ++l) { vA[l] = sA[ry * SP + rx0 + l]; vB[l] = sB[ry * SP + rx0 + l]; }
    }
    __syncthreads();   // all reads done; row buffers may overwrite input tiles
    if (tid < IN * 4) {
        #pragma unroll
        for (int j = 0; j < 8; ++j) {
            float a1 = 0.f, a2 = 0.f;
            #pragma unroll
            for (int k = 0; k < 11; ++k) {
                float g = gw.g[k];
                a1 = fmaf(g, vA[j + k], a1);
                a2 = fmaf(g, vB[j + k], a2);
            }
            r1[ry * RP + rx0 + j] = a1;
            r2[ry * RP + rx0 + j] = a2;
        }
        // in-place: vA <- A^2+B^2, vB <- A*B
        #pragma unroll
        for (int l = 0; l < 18; ++l) {
            float p = vA[l] * vB[l];
            vA[l] = fmaf(vA[l], vA[l], vB[l] * vB[l]);
            vB[l] = p;
        }
        #pragma unroll
        for (int j = 0; j < 8; ++j) {
            float aSS = 0.f, a12 = 0.f;
            #pragma unroll
            for (int k = 0; k < 11; ++k) {
                float g = gw.g[k];
                aSS = fmaf(g, vA[j + k], aSS);
                a12 = fmaf(g, vB[j + k], a12);
            }
            rSS[ry * RP + rx0 + j] = aSS;
            r12[ry * RP + rx0 + j] = a12;
        }
    }
    __syncthreads();

    // Col conv: all 256 threads, 4 outputs each
    const int y0 = (tid >> 5) * 4, x = tid & 31;
    float lss = 0.f, lmc = 0.f;
    {
        auto cconv = [&](const float* R, float* O) {
            float v[14];
            #pragma unroll
            for (int l = 0; l < 14; ++l) v[l] = R[(y0 + l) * RP + x];
            #pragma unroll
            for (int j = 0; j < 4; ++j) {
                float a = 0.f;
                #pragma unroll
                for (int k = 0; k < 11; ++k) a = fmaf(gw.g[k], v[j + k], a);
                O[j] = a;
            }
        };
        float muA[4], muB[4], qSS[4], qAB[4];
        cconv(r1, muA); cconv(r2, muB); cconv(rSS, qSS); cconv(r12, qAB);
        #pragma unroll
        for (int j = 0; j < 4; ++j) {
            float m1 = muA[j], m2 = muB[j];
            float P = m1 * m2;
            float S = fmaf(m1, m1, m2 * m2);
            float V1 = 2.f * (qAB[j] - P) + 58.5225f;
            float V2 = (qSS[j] - S) + 58.5225f;
            float num = (2.f * P + 6.5025f) * V1;
            float SC = S + 6.5025f;
            float inv = 1.f / (SC * V2);
            lss = fmaf(num, inv, lss);
            lmc = fmaf(V1 * SC, inv, lmc);
        }
    }
    #pragma unroll
    for (int o = 32; o > 0; o >>= 1) { lss += __shfl_down(lss, o); lmc += __shfl_down(lmc, o); }
    if ((tid & 63) == 0) { red[(tid >> 6) * 2] = lss; red[(tid >> 6) * 2 + 1] = lmc; }
    __syncthreads();
    if (tid == 0) {
        float a = red[0] + red[2] + red[4] + red[6];
        float m = red[1] + red[3] + red[5] + red[7];
        int stripe = bid & 63;
        atomicAdd(&acc[(0 + level) * 64 + stripe], (double)a);
        atomicAdd(&acc[(5 + level) * 64 + stripe], (double)m);
    }
}

// ---------------- 2x2 average pool (both images in one launch) ---------------
__global__ __launch_bounds__(256) void pool_kernel(
    const float* __restrict__ inA, float* __restrict__ outA,
    const float* __restrict__ inB, float* __restrict__ outB,
    int Ho, int n)
{
    const int Wi = Ho * 2;
    const int hw = Ho * Ho;
    const int stride = gridDim.x * blockDim.x;
    for (int idx = blockIdx.x * blockDim.x + threadIdx.x; idx < 2 * n; idx += stride) {
        int k = idx;
        const float2* in2; float* o;
        if (k < n) { in2 = (const float2*)inA; o = outA; }
        else       { k -= n; in2 = (const float2*)inB; o = outB; }
        int p = k / hw; int r = k - p * hw;
        int y = r / Ho; int x = r - y * Ho;
        size_t b2 = (size_t)p * (size_t)(Wi * (Wi / 2)) + (size_t)y * Wi + x;
        float2 u = in2[b2];
        float2 v = in2[b2 + (Wi >> 1)];
        o[k] = 0.25f * ((u.x + u.y) + (v.x + v.y));
    }
}

// ---------------- CLR loss: 29-tap fused tiled separable conv ----------------
#define CLR_IN 60
#define CLR_SP 61
#define CLR_RP 33

__device__ __forceinline__ void clr_load_tile(const float* __restrict__ img, float* s,
                                              int tid, int oy, int ox, size_t base)
{
    for (int i = tid; i < CLR_IN * CLR_IN; i += 256) {
        int y = i / CLR_IN, x = i - y * CLR_IN;
        int gy = oy + y, gx = ox + x;
        bool ok = (gy >= 0) && (gy < 512) && (gx >= 0) && (gx < 512);
        s[y * CLR_SP + x] = ok ? img[base + (size_t)gy * 512 + gx] : 0.f;
    }
}

__device__ __forceinline__ void clr_rowconv(const float* s, float* rbuf, const GW29& gw, int tid)
{
    if (tid < 240) {
        int y = tid >> 2, x0 = (tid & 3) * 8;
        float v[36];
        #pragma unroll
        for (int l = 0; l < 36; ++l) v[l] = s[y * CLR_SP + x0 + l];
        #pragma unroll
        for (int j = 0; j < 8; ++j) {
            float a = 0.f;
            #pragma unroll
            for (int k = 0; k < 29; ++k) a = fmaf(gw.g[k], v[j + k], a);
            rbuf[y * CLR_RP + x0 + j] = a;
        }
    }
}

__device__ __forceinline__ void clr_colconv(const float* rbuf, const GW29& gw, int y0, int x, float mu[4])
{
    float v[32];
    #pragma unroll
    for (int l = 0; l < 32; ++l) v[l] = rbuf[(y0 + l) * CLR_RP + x];
    #pragma unroll
    for (int j = 0; j < 4; ++j) {
        float a = 0.f;
        #pragma unroll
        for (int k = 0; k < 29; ++k) a = fmaf(gw.g[k], v[j + k], a);
        mu[j] = a;
    }
}

template<bool STOREP>
__global__ __launch_bounds__(256) void clr_stage0(
    const float* __restrict__ img1, __half* __restrict__ pbuf,
    GW29 gw, double* __restrict__ acc)
{
    __shared__ float s[CLR_IN * CLR_SP];
    __shared__ float rbuf[CLR_IN * CLR_RP];
    __shared__ float red[4];
    const int tid = threadIdx.x, bid = blockIdx.x;
    const int plane = bid >> 8, t = bid & 255;
    const int ty = t >> 4, tx = t & 15;
    const int b = plane / 3, c = plane - b * 3;
    const float wg = (c == 0) ? 0.299f : (c == 1 ? 0.587f : 0.144f);
    const size_t base = (size_t)plane * (512 * 512);

    clr_load_tile(img1, s, tid, ty * 32 - 14, tx * 32 - 14, base);
    __syncthreads();
    clr_rowconv(s, rbuf, gw, tid);
    __syncthreads();
    const int y0 = (tid >> 5) * 4, x = tid & 31;
    float mu[4];
    clr_colconv(rbuf, gw, y0, x, mu);
    float part = 0.f;
    #pragma unroll
    for (int j = 0; j < 4; ++j) {
        float p = poly5(mu[j]);
        part += p;
        if (STOREP)
            pbuf[base + (size_t)(ty * 32 + y0 + j) * 512 + (tx * 32 + x)] = __float2half(p);
    }
    part *= wg;
    #pragma unroll
    for (int o = 32; o > 0; o >>= 1) part += __shfl_down(part, o);
    if ((tid & 63) == 0) red[tid >> 6] = part;
    __syncthreads();
    if (tid == 0)
        atomicAdd(&acc[(12 + b) * 64 + (bid & 63)], (double)(red[0] + red[1] + red[2] + red[3]));
}

template<bool LOADP>
__global__ __launch_bounds__(256) void clr_stage1(
    const float* __restrict__ img1, const float* __restrict__ img3,
    const __half* __restrict__ pbuf, GW29 gw, double* __restrict__ acc)
{
    __shared__ float s[CLR_IN * CLR_SP];
    __shared__ float rbuf[CLR_IN * CLR_RP];
    __shared__ float red[4];
    __shared__ float sc_sh;
    const int tid = threadIdx.x, bid = blockIdx.x;
    const int plane = bid >> 8, t = bid & 255;
    const int ty = t >> 4, tx = t & 15;
    const int b = plane / 3;
    const size_t base = (size_t)plane * (512 * 512);

    if (tid < 64) {
        double m1 = acc[(12 + b) * 64 + tid];
        double m3 = acc[(28 + b) * 64 + tid];
        #pragma unroll
        for (int o = 32; o > 0; o >>= 1) { m1 += __shfl_down(m1, o); m3 += __shfl_down(m3, o); }
        if (tid == 0) sc_sh = (float)(m1 / m3);
    }

    const int y0 = (tid >> 5) * 4, x = tid & 31;
    float pre[4];
    if (!LOADP) {
        clr_load_tile(img1, s, tid, ty * 32 - 14, tx * 32 - 14, base);
        __syncthreads();
        clr_rowconv(s, rbuf, gw, tid);
        __syncthreads();
        float mu1[4];
        clr_colconv(rbuf, gw, y0, x, mu1);
        #pragma unroll
        for (int j = 0; j < 4; ++j) pre[j] = poly5(mu1[j]);
        __syncthreads();
    }
    clr_load_tile(img3, s, tid, ty * 32 - 14, tx * 32 - 14, base);
    __syncthreads();
    clr_rowconv(s, rbuf, gw, tid);
    __syncthreads();
    float mu3[4];
    clr_colconv(rbuf, gw, y0, x, mu3);
    if (LOADP) {
        #pragma unroll
        for (int j = 0; j < 4; ++j)
            pre[j] = __half2float(pbuf[base + (size_t)(ty * 32 + y0 + j) * 512 + (tx * 32 + x)]);
    }
    const float sc = sc_sh;
    float t1 = 0.f;
    #pragma unroll
    for (int j = 0; j < 4; ++j) t1 += fabsf(pre[j] - mu3[j] * sc);
    #pragma unroll
    for (int o = 32; o > 0; o >>= 1) t1 += __shfl_down(t1, o);
    if ((tid & 63) == 0) red[tid >> 6] = t1;
    __syncthreads();
    if (tid == 0)
        atomicAdd(&acc[11 * 64 + (bid & 63)], (double)(red[0] + red[1] + red[2] + red[3]));
}

// ---------------- Finalize: combine everything into the scalar ---------------
__global__ void finalize_kernel(const double* __restrict__ acc, float* __restrict__ out)
{
    __shared__ double sums[ACC_SLOTS];
    int t = threadIdx.x;
    if (t < ACC_SLOTS) {
        double s = 0.0;
        for (int i = 0; i < 64; ++i) s += acc[t * 64 + i];
        sums[t] = s;
    }
    __syncthreads();
    if (t == 0) {
        const double w[5] = {0.0448, 0.2856, 0.3001, 0.2363, 0.1333};
        double value = 1.0;
        for (int l = 0; l < 5; ++l) {
            double dim = (double)(512 >> l);
            double cnt = 48.0 * dim * dim;
            double mval = (l < 4) ? (sums[5 + l] / cnt) : (sums[l] / cnt);
            value *= pow(mval, w[l]);
        }
        double n0 = 48.0 * 512.0 * 512.0;
        double l1v = sums[10] / n0;
        double clrv = sums[11] / n0;
        out[0] = (float)(0.4 * (1.0 - value) + 0.4 * l1v + 0.2 * clrv);
    }
}

// ---------------- Launch ------------------------------------------------------
extern "C" void kernel_launch(void* const* d_in, const int* in_sizes, int n_in,
                              void* d_out, int out_size, void* d_ws, size_t ws_size,
                              hipStream_t stream)
{
    (void)in_sizes; (void)n_in; (void)out_size;
    const float* img1 = (const float*)d_in[0];
    const float* img2 = (const float*)d_in[1];
    const float* img3 = (const float*)d_in[2];
    float* out = (float*)d_out;
    double* acc = (double*)d_ws;

    GW11 g11; make_gauss(11, 1.5, g11.g);
    GW7  g7;  make_gauss(7, 1.1, g7.g);
    GW29 g29; make_gauss(29, 29.0 / 6.0, g29.g);

    hipMemsetAsync(d_ws, 0, ACC_BYTES, stream);

    // L1 term + me3 (both conv-free reductions)
    l1_kernel<<<2048, 256, 0, stream>>>((const float4*)img1, (const float4*)img2,
                                        (16 * 3 * 512 * 512) / 4, g7, acc);
    me3_kernel<<<1536, 256, 0, stream>>>((const float4*)img3, g29, acc);

    // MS-SSIM: 5 levels with interleaved 2x2 pooling into workspace pyramid
    float* pyr = (float*)((char*)d_ws + 32768);
    const size_t PYR1 = (size_t)16 * 3 * (256 * 256 + 128 * 128 + 64 * 64 + 32 * 32);
    float* pyrA = pyr;
    float* pyrB = pyr + PYR1;

    const float* curA = img1; const float* curB = img2;
    int H = 512; size_t off = 0;
    for (int l = 0; l < 5; ++l) {
        int tilesX = H / 32; int tpp = tilesX * tilesX;
        ssim_kernel<<<48 * tpp, 256, 0, stream>>>(curA, curB, H, tpp, tilesX, g11, acc, l);
        if (l < 4) {
            int Ho = H / 2; int n = 48 * Ho * Ho;
            float* dA = pyrA + off; float* dB = pyrB + off;
            int blocks = (2 * n + 255) / 256; if (blocks > 4096) blocks = 4096;
            pool_kernel<<<blocks, 256, 0, stream>>>(curA, dA, curB, dB, Ho, n);
            curA = dA; curB = dB; off += (size_t)n; H = Ho;
        }
    }

    // CLR: stage0 conv(img1)->p (+me1); stage1 conv(img3)+|p - mu3*sc|
    const size_t poff = 32768 + PYR1 * 2 * sizeof(float);
    const size_t PBYTES = (size_t)48 * 512 * 512 * sizeof(__half);
    __half* pbuf = (__half*)((char*)d_ws + poff);
    if (ws_size >= poff + PBYTES) {
        clr_stage0<true><<<12288, 256, 0, stream>>>(img1, pbuf, g29, acc);
        clr_stage1<true><<<12288, 256, 0, stream>>>(img1, img3, pbuf, g29, acc);
    } else {
        clr_stage0<false><<<12288, 256, 0, stream>>>(img1, pbuf, g29, acc);
        clr_stage1<false><<<12288, 256, 0, stream>>>(img1, img3, pbuf, g29, acc);
    }

    finalize_kernel<<<1, 64, 0, stream>>>(acc, out);
}

// Round 4
// 236.289 us; speedup vs baseline: 2.4554x; 1.5348x over previous
//
#include <hip/hip_runtime.h>
#include <hip/hip_fp16.h>
#include <cmath>

typedef float f2 __attribute__((ext_vector_type(2)));

// ---------------- Gaussian windows (host-computed, passed by value) ----------
struct GW7  { float g[7];  };
struct GW11 { float g[11]; };
struct GW29 { float g[29]; };

static void make_gauss(int ws, double sigma, float* out) {
    double t[32]; double s = 0.0;
    int c = ws / 2;
    for (int i = 0; i < ws; ++i) { double d = i - c; t[i] = exp(-(d * d) / (2.0 * sigma * sigma)); s += t[i]; }
    for (int i = 0; i < ws; ++i) out[i] = (float)(t[i] / s);
}

// Accumulator slots (each striped x64 doubles):
// 0-4: ssim[level]  5-9: mcs[level]  10: l1  11: clr  12-27: me1[b]  28-43: me3[b]
#define ACC_SLOTS 44
#define ACC_BYTES (ACC_SLOTS * 64 * sizeof(double))

__device__ __forceinline__ float poly5(float x) {
    float r = fmaf(1.556091f, x, -1.894404f);
    r = fmaf(r, x, 1.435936f);
    r = fmaf(r, x, -0.173433f);
    r = fmaf(r, x, 0.07633f);
    r = fmaf(r, x, -0.000519f);
    return r;
}

__device__ __forceinline__ float border7(int p, const GW7& gw) {
    if (p >= 3 && p <= 508) return 1.f;
    float r = 0.f;
    #pragma unroll
    for (int k = 0; k < 7; ++k) { int q = p + 3 - k; if (q >= 0 && q < 512) r += gw.g[k]; }
    return r;
}

// ---------------- SSIM per level: packed fused tiled separable conv ----------
// f2 = (A, B). Quantities: conv(A,B) packed, conv(A^2+B^2, A*B) packed.
// Fused extras: 2x2 avg-pool output (levels 0-3) and L1 term (level 0).
template<bool INTER>
__global__ __launch_bounds__(256) void ssim_kernel(
    const float* __restrict__ Aim, const float* __restrict__ Bim, const f2* __restrict__ AB,
    int H, int tpp, int tilesX, GW11 gw, GW7 g7, double* __restrict__ acc, int level,
    f2* __restrict__ pooled, int Ho)
{
    constexpr int TILE = 32, IN = 42, SP2 = 46, RP2 = 34;
    __shared__ f2 lds[2 * IN * RP2];             // 2856 f2 = 22.8 KB (union)
    __shared__ float red[12];
    f2* s    = lds;                              // load phase: 42 x 46
    f2* r_mu = lds;                              // conv phase: 42 x 34
    f2* r_sq = lds + IN * RP2;

    const int tid = threadIdx.x;
    const int bid = blockIdx.x;
    const int plane = bid / tpp;
    const int t = bid - plane * tpp;
    const int ty = t / tilesX, tx = t - ty * tilesX;
    const size_t base = (size_t)plane * H * H;
    const int oy = ty * TILE - 5, ox = tx * TILE - 5;

    for (int i = tid; i < IN * IN; i += 256) {
        int y = i / IN, x = i - y * IN;
        int gy = oy + y, gx = ox + x;
        bool ok = (gy >= 0) && (gy < H) && (gx >= 0) && (gx < H);
        size_t o = base + (size_t)gy * H + gx;
        f2 v = {0.f, 0.f};
        if (ok) {
            if (INTER) v = AB[o];
            else { v.x = Aim[o]; v.y = Bim[o]; }
        }
        s[y * SP2 + x] = v;
    }
    __syncthreads();

    // ---- phase A: snapshot row-conv inputs; pool; L1 (all read s) ----
    f2 v[18];
    const int ry = tid >> 2, rx0 = (tid & 3) * 8;
    if (tid < IN * 4) {
        #pragma unroll
        for (int l = 0; l < 18; ++l) v[l] = s[ry * SP2 + rx0 + l];
    }
    if (pooled) {
        int py = tid >> 4, px = tid & 15;
        int a = (5 + 2 * py) * SP2 + 5 + 2 * px;
        f2 u = s[a] + s[a + 1] + s[a + SP2] + s[a + SP2 + 1];
        pooled[(size_t)plane * Ho * Ho + (size_t)(ty * 16 + py) * Ho + (tx * 16 + px)] = 0.25f * u;
    }
    float l1p = 0.f;
    if (level == 0) {
        #pragma unroll
        for (int jj = 0; jj < 4; ++jj) {
            int p = jj * 256 + tid;
            int py = p >> 5, px = p & 31;
            f2 u = s[(5 + py) * SP2 + 5 + px];
            float w = border7(ty * 32 + py, g7) * border7(tx * 32 + px, g7);
            l1p += w * fabsf(u.x - u.y);
        }
    }
    __syncthreads();   // all s reads done; row buffers may overwrite s

    // ---- phase B: packed row conv ----
    if (tid < IN * 4) {
        #pragma unroll
        for (int j = 0; j < 8; ++j) {
            f2 a = {0.f, 0.f};
            #pragma unroll
            for (int k = 0; k < 11; ++k) a = gw.g[k] * v[j + k] + a;
            r_mu[ry * RP2 + rx0 + j] = a;
        }
        #pragma unroll
        for (int l = 0; l < 18; ++l) {
            f2 w;
            w.x = fmaf(v[l].x, v[l].x, v[l].y * v[l].y);
            w.y = v[l].x * v[l].y;
            v[l] = w;
        }
        #pragma unroll
        for (int j = 0; j < 8; ++j) {
            f2 a = {0.f, 0.f};
            #pragma unroll
            for (int k = 0; k < 11; ++k) a = gw.g[k] * v[j + k] + a;
            r_sq[ry * RP2 + rx0 + j] = a;
        }
    }
    __syncthreads();

    // ---- phase C: packed col conv + pointwise ----
    const int y0 = (tid >> 5) * 4, x = tid & 31;
    float lss = 0.f, lmc = 0.f;
    {
        f2 mu[4], q[4];
        {
            f2 u[14];
            #pragma unroll
            for (int l = 0; l < 14; ++l) u[l] = r_mu[(y0 + l) * RP2 + x];
            #pragma unroll
            for (int j = 0; j < 4; ++j) {
                f2 a = {0.f, 0.f};
                #pragma unroll
                for (int k = 0; k < 11; ++k) a = gw.g[k] * u[j + k] + a;
                mu[j] = a;
            }
        }
        {
            f2 u[14];
            #pragma unroll
            for (int l = 0; l < 14; ++l) u[l] = r_sq[(y0 + l) * RP2 + x];
            #pragma unroll
            for (int j = 0; j < 4; ++j) {
                f2 a = {0.f, 0.f};
                #pragma unroll
                for (int k = 0; k < 11; ++k) a = gw.g[k] * u[j + k] + a;
                q[j] = a;
            }
        }
        #pragma unroll
        for (int j = 0; j < 4; ++j) {
            float m1 = mu[j].x, m2 = mu[j].y;
            float P = m1 * m2;
            float S = fmaf(m1, m1, m2 * m2);
            float V1 = 2.f * (q[j].y - P) + 58.5225f;
            float V2 = (q[j].x - S) + 58.5225f;
            float num = (2.f * P + 6.5025f) * V1;
            float SC = S + 6.5025f;
            float inv = __builtin_amdgcn_rcpf(SC * V2);
            lss = fmaf(num, inv, lss);
            lmc = fmaf(V1 * SC, inv, lmc);
        }
    }
    #pragma unroll
    for (int o = 32; o > 0; o >>= 1) {
        lss += __shfl_down(lss, o); lmc += __shfl_down(lmc, o); l1p += __shfl_down(l1p, o);
    }
    if ((tid & 63) == 0) {
        int g = tid >> 6;
        red[g * 3] = lss; red[g * 3 + 1] = lmc; red[g * 3 + 2] = l1p;
    }
    __syncthreads();
    if (tid == 0) {
        float a = red[0] + red[3] + red[6] + red[9];
        float m = red[1] + red[4] + red[7] + red[10];
        int stripe = bid & 63;
        atomicAdd(&acc[(0 + level) * 64 + stripe], (double)a);
        atomicAdd(&acc[(5 + level) * 64 + stripe], (double)m);
        if (level == 0) {
            float l1 = red[2] + red[5] + red[8] + red[11];
            atomicAdd(&acc[10 * 64 + stripe], (double)l1);
        }
    }
}

// ---------------- CLR: packed (img1,img3) 29-tap fused separable conv --------
// MODE 0: store half2(p, mu3) + accumulate me1/me3
// MODE 1: accumulate me1/me3 only (fallback pass 1)
// MODE 2: recompute + accumulate |p - mu3*sc| (fallback pass 2)
template<int MODE>
__global__ __launch_bounds__(256) void clr_conv(
    const float* __restrict__ img1, const float* __restrict__ img3,
    __half2* __restrict__ pbuf, GW29 gw, double* __restrict__ acc)
{
    constexpr int IN = 60, SP2 = 62, RP2 = 34;
    __shared__ f2 lds[IN * SP2];                 // 3720 f2 = 29.8 KB (union)
    __shared__ float red[8];
    __shared__ float sc_sh;
    f2* s = lds;
    f2* r = lds;                                 // conv phase: 60 x 34

    const int tid = threadIdx.x, bid = blockIdx.x;
    const int plane = bid >> 8, t = bid & 255;
    const int ty = t >> 4, tx = t & 15;
    const int b = plane / 3, c = plane - b * 3;
    const float wg = (c == 0) ? 0.299f : (c == 1 ? 0.587f : 0.144f);
    const size_t base = (size_t)plane * (512 * 512);
    const int oy = ty * 32 - 14, ox = tx * 32 - 14;

    if (MODE == 2 && tid < 64) {
        double m1 = acc[(12 + b) * 64 + tid];
        double m3 = acc[(28 + b) * 64 + tid];
        #pragma unroll
        for (int o = 32; o > 0; o >>= 1) { m1 += __shfl_down(m1, o); m3 += __shfl_down(m3, o); }
        if (tid == 0) sc_sh = (float)(m1 / m3);
    }

    for (int i = tid; i < IN * IN; i += 256) {
        int y = i / IN, x = i - y * IN;
        int gy = oy + y, gx = ox + x;
        bool ok = (gy >= 0) && (gy < 512) && (gx >= 0) && (gx < 512);
        size_t o = base + (size_t)gy * 512 + gx;
        f2 v = {0.f, 0.f};
        if (ok) { v.x = img1[o]; v.y = img3[o]; }
        s[y * SP2 + x] = v;
    }
    __syncthreads();

    f2 v[36];
    const int ry = tid >> 2, rx0 = (tid & 3) * 8;
    if (tid < IN * 4) {
        #pragma unroll
        for (int l = 0; l < 36; ++l) v[l] = s[ry * SP2 + rx0 + l];
    }
    __syncthreads();
    if (tid < IN * 4) {
        #pragma unroll
        for (int j = 0; j < 8; ++j) {
            f2 a = {0.f, 0.f};
            #pragma unroll
            for (int k = 0; k < 29; ++k) a = gw.g[k] * v[j + k] + a;
            r[ry * RP2 + rx0 + j] = a;
        }
    }
    __syncthreads();

    const int y0 = (tid >> 5) * 4, x = tid & 31;
    f2 mu[4];
    {
        f2 u[32];
        #pragma unroll
        for (int l = 0; l < 32; ++l) u[l] = r[(y0 + l) * RP2 + x];
        #pragma unroll
        for (int j = 0; j < 4; ++j) {
            f2 a = {0.f, 0.f};
            #pragma unroll
            for (int k = 0; k < 29; ++k) a = gw.g[k] * u[j + k] + a;
            mu[j] = a;
        }
    }
    float p1 = 0.f, p3 = 0.f;
    #pragma unroll
    for (int j = 0; j < 4; ++j) {
        float p = poly5(mu[j].x);
        if (MODE == 2) {
            p1 += fabsf(p - mu[j].y * sc_sh);
        } else {
            p1 += p; p3 += mu[j].y;
            if (MODE == 0)
                pbuf[base + (size_t)(ty * 32 + y0 + j) * 512 + (tx * 32 + x)] =
                    __floats2half2_rn(p, mu[j].y);
        }
    }
    if (MODE != 2) { p1 *= wg; p3 *= wg; }
    #pragma unroll
    for (int o = 32; o > 0; o >>= 1) { p1 += __shfl_down(p1, o); p3 += __shfl_down(p3, o); }
    if ((tid & 63) == 0) { red[(tid >> 6) * 2] = p1; red[(tid >> 6) * 2 + 1] = p3; }
    __syncthreads();
    if (tid == 0) {
        float a1 = red[0] + red[2] + red[4] + red[6];
        int stripe = bid & 63;
        if (MODE == 2) {
            atomicAdd(&acc[11 * 64 + stripe], (double)a1);
        } else {
            float a3 = red[1] + red[3] + red[5] + red[7];
            atomicAdd(&acc[(12 + b) * 64 + stripe], (double)a1);
            atomicAdd(&acc[(28 + b) * 64 + stripe], (double)a3);
        }
    }
}

// ---------------- CLR finish: |p - mu3*sc| over stored half2 -----------------
__global__ __launch_bounds__(256) void clr_fin(
    const __half2* __restrict__ pbuf, double* __restrict__ acc)
{
    __shared__ float red[4];
    __shared__ float sc_sh;
    const int tid = threadIdx.x, bid = blockIdx.x;
    const int b = bid / 192, sub = bid - b * 192;
    if (tid < 64) {
        double m1 = acc[(12 + b) * 64 + tid];
        double m3 = acc[(28 + b) * 64 + tid];
        #pragma unroll
        for (int o = 32; o > 0; o >>= 1) { m1 += __shfl_down(m1, o); m3 += __shfl_down(m3, o); }
        if (tid == 0) sc_sh = (float)(m1 / m3);
    }
    __syncthreads();
    const float sc = sc_sh;
    const size_t bo = (size_t)b * 786432 + (size_t)sub * 4096;
    float s = 0.f;
    #pragma unroll
    for (int it = 0; it < 8; ++it) {
        size_t i = bo + it * 512 + tid * 2;
        float2 a = __half22float2(pbuf[i]);
        float2 c = __half22float2(pbuf[i + 1]);
        s += fabsf(a.x - a.y * sc) + fabsf(c.x - c.y * sc);
    }
    #pragma unroll
    for (int o = 32; o > 0; o >>= 1) s += __shfl_down(s, o);
    if ((tid & 63) == 0) red[tid >> 6] = s;
    __syncthreads();
    if (tid == 0)
        atomicAdd(&acc[11 * 64 + (bid & 63)], (double)(red[0] + red[1] + red[2] + red[3]));
}

// ---------------- Finalize: combine everything into the scalar ---------------
__global__ void finalize_kernel(const double* __restrict__ acc, float* __restrict__ out)
{
    __shared__ double sums[ACC_SLOTS];
    int t = threadIdx.x;
    if (t < ACC_SLOTS) {
        double s = 0.0;
        for (int i = 0; i < 64; ++i) s += acc[t * 64 + i];
        sums[t] = s;
    }
    __syncthreads();
    if (t == 0) {
        const double w[5] = {0.0448, 0.2856, 0.3001, 0.2363, 0.1333};
        double value = 1.0;
        for (int l = 0; l < 5; ++l) {
            double dim = (double)(512 >> l);
            double cnt = 48.0 * dim * dim;
            double mval = (l < 4) ? (sums[5 + l] / cnt) : (sums[l] / cnt);
            value *= pow(mval, w[l]);
        }
        double n0 = 48.0 * 512.0 * 512.0;
        double l1v = sums[10] / n0;
        double clrv = sums[11] / n0;
        out[0] = (float)(0.4 * (1.0 - value) + 0.4 * l1v + 0.2 * clrv);
    }
}

// ---------------- Launch ------------------------------------------------------
extern "C" void kernel_launch(void* const* d_in, const int* in_sizes, int n_in,
                              void* d_out, int out_size, void* d_ws, size_t ws_size,
                              hipStream_t stream)
{
    (void)in_sizes; (void)n_in; (void)out_size;
    const float* img1 = (const float*)d_in[0];
    const float* img2 = (const float*)d_in[1];
    const float* img3 = (const float*)d_in[2];
    float* out = (float*)d_out;
    double* acc = (double*)d_ws;

    GW11 g11; make_gauss(11, 1.5, g11.g);
    GW7  g7;  make_gauss(7, 1.1, g7.g);
    GW29 g29; make_gauss(29, 29.0 / 6.0, g29.g);

    hipMemsetAsync(d_ws, 0, ACC_BYTES, stream);

    // Interleaved (A,B) float2 pyramid for levels 1..4
    f2* pyr = (f2*)((char*)d_ws + 32768);
    size_t offs[4];
    offs[0] = 0;
    offs[1] = offs[0] + (size_t)48 * 256 * 256;
    offs[2] = offs[1] + (size_t)48 * 128 * 128;
    offs[3] = offs[2] + (size_t)48 * 64 * 64;
    const size_t PYRF2 = offs[3] + (size_t)48 * 32 * 32;

    // MS-SSIM levels (pool + L1 fused into the conv kernels)
    const f2* cur = nullptr;
    int H = 512;
    for (int l = 0; l < 5; ++l) {
        int tilesX = H / 32; int tpp = tilesX * tilesX;
        f2* pooled = (l < 4) ? (pyr + offs[l]) : nullptr;
        int Ho = H / 2;
        if (l == 0)
            ssim_kernel<false><<<48 * tpp, 256, 0, stream>>>(
                img1, img2, nullptr, H, tpp, tilesX, g11, g7, acc, l, pooled, Ho);
        else
            ssim_kernel<true><<<48 * tpp, 256, 0, stream>>>(
                nullptr, nullptr, cur, H, tpp, tilesX, g11, g7, acc, l, pooled, Ho);
        cur = pooled; H = Ho;
    }

    // CLR: one fused packed conv + cheap finish (fallback recomputes)
    const size_t poff = 32768 + PYRF2 * sizeof(f2);
    const size_t PBYTES = (size_t)48 * 512 * 512 * sizeof(__half2);
    __half2* pbuf = (__half2*)((char*)d_ws + poff);
    if (ws_size >= poff + PBYTES) {
        clr_conv<0><<<12288, 256, 0, stream>>>(img1, img3, pbuf, g29, acc);
        clr_fin<<<3072, 256, 0, stream>>>(pbuf, acc);
    } else {
        clr_conv<1><<<12288, 256, 0, stream>>>(img1, img3, pbuf, g29, acc);
        clr_conv<2><<<12288, 256, 0, stream>>>(img1, img3, pbuf, g29, acc);
    }

    finalize_kernel<<<1, 64, 0, stream>>>(acc, out);
}